// Round 6
// baseline (824.036 us; speedup 1.0000x reference)
//
#include <hip/hip_runtime.h>
#include <hip/hip_bf16.h>

typedef short bf16x8 __attribute__((ext_vector_type(8)));   // 8 bf16 in 4 VGPRs
typedef float f32x4 __attribute__((ext_vector_type(4)));

#define NV 1000
#define ND 1024
#define NT 800
#define NB 64

__device__ inline unsigned short f32_bf16(float f) {
    unsigned u = __builtin_bit_cast(unsigned, f);
    return (unsigned short)((u + 0x7FFFu + ((u >> 16) & 1u)) >> 16);
}
__device__ inline void split_bf16(float f, unsigned short& h, unsigned short& l) {
    unsigned u = __builtin_bit_cast(unsigned, f);
    unsigned hb = (u + 0x7FFFu + ((u >> 16) & 1u)) >> 16;
    h = (unsigned short)hb;
    float hf = __builtin_bit_cast(float, hb << 16);
    float lf = f - hf;
    unsigned ul = __builtin_bit_cast(unsigned, lf);
    l = (unsigned short)((ul + 0x7FFFu + ((ul >> 16) & 1u)) >> 16);
}

__device__ inline void gload16(const void* g, void* l) {
    __builtin_amdgcn_global_load_lds(
        (const __attribute__((address_space(1))) unsigned int*)g,
        (__attribute__((address_space(3))) unsigned int*)l, 16, 0, 0);
}

// ---------------- prep_q: pad Q (1000x1024) to 1024 rows, split into bf16 hi/lo
__global__ __launch_bounds__(256) void prep_q(const float* __restrict__ Q,
                                              unsigned short* __restrict__ Qh,
                                              unsigned short* __restrict__ Ql) {
    int idx = blockIdx.x * 256 + threadIdx.x;
    int row = idx >> 8;
    int c4 = (idx & 255) << 2;
    float4 f = make_float4(0.f, 0.f, 0.f, 0.f);
    if (row < NV) f = *(const float4*)(Q + (size_t)row * ND + c4);
    unsigned short h0,h1,h2,h3,l0,l1,l2,l3;
    split_bf16(f.x,h0,l0); split_bf16(f.y,h1,l1);
    split_bf16(f.z,h2,l2); split_bf16(f.w,h3,l3);
    *(ushort4*)(Qh + (size_t)row * ND + c4) = make_ushort4(h0,h1,h2,h3);
    *(ushort4*)(Ql + (size_t)row * ND + c4) = make_ushort4(l0,l1,l2,l3);
}

// ---------------- prep_c: transpose C[b] (1024,800) -> Ct[b] (800,1024) bf16 hi/lo
// Also (fast path) writes Cbf = bf16 copy of C in original [d][t] layout.
__global__ __launch_bounds__(256) void prep_c(const float* __restrict__ C,
                                              unsigned short* __restrict__ Cth,
                                              unsigned short* __restrict__ Ctl,
                                              unsigned short* __restrict__ Cbf,
                                              int writeCbf) {
    const int dt = blockIdx.x;   // 0..15
    const int tt = blockIdx.y;   // 0..24
    const int b  = blockIdx.z;
    const int tid = threadIdx.x;
    __shared__ float T[64][33];
    const float* Cb = C + (size_t)b * ND * NT;
    const int d0 = dt * 64, t0 = tt * 32;
#pragma unroll
    for (int r = 0; r < 2; ++r) {
        int idx = r * 256 + tid;
        int row = idx >> 3;               // d within tile, 0..63
        int c4 = (idx & 7) << 2;          // t within tile
        float4 f = *(const float4*)(Cb + (size_t)(d0 + row) * NT + t0 + c4);
        T[row][c4 + 0] = f.x; T[row][c4 + 1] = f.y;
        T[row][c4 + 2] = f.z; T[row][c4 + 3] = f.w;
        if (writeCbf) {
            *(ushort4*)(Cbf + ((size_t)b * ND + d0 + row) * NT + t0 + c4) =
                make_ushort4(f32_bf16(f.x), f32_bf16(f.y), f32_bf16(f.z), f32_bf16(f.w));
        }
    }
    __syncthreads();
#pragma unroll
    for (int r = 0; r < 2; ++r) {
        int idx = r * 256 + tid;
        int trow = idx >> 4;              // t within tile, 0..31
        int dc = (idx & 15) << 2;         // d within tile
        unsigned short h[4], l[4];
#pragma unroll
        for (int j = 0; j < 4; ++j) split_bf16(T[dc + j][trow], h[j], l[j]);
        size_t o = ((size_t)b * NT + t0 + trow) * ND + d0 + dc;
        *(ushort4*)(Cth + o) = make_ushort4(h[0],h[1],h[2],h[3]);
        *(ushort4*)(Ctl + o) = make_ushort4(l[0],l[1],l[2],l[3]);
    }
}

// ---------------- GEMM1: S[b](1000x800) = Q(1000x1024) @ C[b](1024x800)
// 3-term bf16 split. Counted-vmcnt pipeline: raw s_barrier, loads for tile t+1
// stay in flight across the barriers (never vmcnt(0) in the loop).
// Staging flattened to 36 issues = 9 per wave -> exact per-wave vmcnt(9).
__global__ __launch_bounds__(256) void gemm1_kernel(const unsigned short* __restrict__ Qh,
                                                    const unsigned short* __restrict__ Ql,
                                                    const unsigned short* __restrict__ Cth,
                                                    const unsigned short* __restrict__ Ctl,
                                                    float* __restrict__ S) {
    const int h = blockIdx.x;
    const int L = (h & 7) * 320 + (h >> 3);
    const int bm = L & 7;
    const int rest = L >> 3;
    const int bn = rest % 5;
    const int b  = rest / 5;

    const int tid = threadIdx.x;
    const int lane = tid & 63;
    const int w = tid >> 6;
    const int wr = w >> 1, wc = w & 1;

    // per buffer (ushort idx): Ah 0 | Al 4096 | Bh 8192 | Bl 13312; 18432 total (36KB) x2
    __shared__ unsigned short lds[2 * 18432];

    const int v0 = bm * 128, t0 = bn * 160;
    const unsigned short* Agh = Qh + (size_t)v0 * ND;
    const unsigned short* Agl = Ql + (size_t)v0 * ND;
    const unsigned short* Bgh = Cth + ((size_t)b * NT + t0) * ND;
    const unsigned short* Bgl = Ctl + ((size_t)b * NT + t0) * ND;

    f32x4 acc[4][5];
#pragma unroll
    for (int i = 0; i < 4; ++i)
#pragma unroll
        for (int j = 0; j < 5; ++j) acc[i][j] = (f32x4){0.f, 0.f, 0.f, 0.f};

    const int srow = lane >> 2;
    const int sslot = lane & 3;
    const int swz = (sslot ^ (srow & 3) ^ ((srow >> 2) & 3)) << 3;
    const int g = lane >> 4, rl = lane & 15;
    const int sx = (g ^ (rl & 3) ^ ((rl >> 2) & 3)) << 4;

#define G1_STAGE(K0, BUF)                                                      \
    {                                                                          \
        unsigned short* Lb = lds + (BUF) * 18432;                              \
        _Pragma("unroll")                                                      \
        for (int j = 0; j < 9; ++j) {                                          \
            int k = w * 9 + j;                                                 \
            const unsigned short* src;                                         \
            unsigned short* dst;                                               \
            if (k < 8)       { src = Agh + (size_t)(k * 16 + srow) * ND;          dst = Lb + k * 512; }             \
            else if (k < 16) { src = Agl + (size_t)((k - 8) * 16 + srow) * ND;    dst = Lb + 4096 + (k - 8) * 512; } \
            else if (k < 26) { src = Bgh + (size_t)((k - 16) * 16 + srow) * ND;   dst = Lb + 8192 + (k - 16) * 512; } \
            else             { src = Bgl + (size_t)((k - 26) * 16 + srow) * ND;   dst = Lb + 13312 + (k - 26) * 512; } \
            gload16(src + swz + (K0), dst);                                    \
        }                                                                      \
    }

#define G1_COMPUTE(BUF)                                                       \
    {                                                                         \
        const char* Lb = (const char*)(lds + (BUF) * 18432);                  \
        bf16x8 ah[4], al[4], bh[5], bl[5];                                    \
        _Pragma("unroll")                                                     \
        for (int mf = 0; mf < 4; ++mf) {                                      \
            int off = (wr * 64 + mf * 16 + rl) * 64 + sx;                     \
            ah[mf] = *(const bf16x8*)(Lb + off);                              \
            al[mf] = *(const bf16x8*)(Lb + 8192 + off);                       \
        }                                                                     \
        _Pragma("unroll")                                                     \
        for (int nf = 0; nf < 5; ++nf) {                                      \
            int off = (wc * 80 + nf * 16 + rl) * 64 + sx;                     \
            bh[nf] = *(const bf16x8*)(Lb + 16384 + off);                      \
            bl[nf] = *(const bf16x8*)(Lb + 26624 + off);                      \
        }                                                                     \
        _Pragma("unroll")                                                     \
        for (int mf = 0; mf < 4; ++mf)                                        \
            _Pragma("unroll")                                                 \
            for (int nf = 0; nf < 5; ++nf) {                                  \
                acc[mf][nf] = __builtin_amdgcn_mfma_f32_16x16x32_bf16(ah[mf], bh[nf], acc[mf][nf], 0, 0, 0); \
                acc[mf][nf] = __builtin_amdgcn_mfma_f32_16x16x32_bf16(ah[mf], bl[nf], acc[mf][nf], 0, 0, 0); \
                acc[mf][nf] = __builtin_amdgcn_mfma_f32_16x16x32_bf16(al[mf], bh[nf], acc[mf][nf], 0, 0, 0); \
            }                                                                 \
    }

    G1_STAGE(0, 0);
    int cur = 0;
#pragma unroll 1
    for (int t = 0; t < 31; ++t) {
        G1_STAGE((t + 1) * 32, cur ^ 1);
        // tile t's 9 loads retired (<=9 outstanding = tile t+1's); t+1's stay in flight
        asm volatile("s_waitcnt vmcnt(9)\n\ts_barrier" ::: "memory");
        G1_COMPUTE(cur);
        // all ds_reads of buf cur retired before anyone overwrites it next iter
        asm volatile("s_waitcnt lgkmcnt(0)\n\ts_barrier" ::: "memory");
        cur ^= 1;
    }
    asm volatile("s_waitcnt vmcnt(0)\n\ts_barrier" ::: "memory");
    G1_COMPUTE(cur);

    float* Sb = S + (size_t)b * NV * NT;
#pragma unroll
    for (int mf = 0; mf < 4; ++mf) {
#pragma unroll
        for (int nf = 0; nf < 5; ++nf) {
#pragma unroll
            for (int r = 0; r < 4; ++r) {
                int v = v0 + wr * 64 + mf * 16 + g * 4 + r;
                int t = t0 + wc * 80 + nf * 16 + rl;
                if (v < NV) Sb[(size_t)v * NT + t] = acc[mf][nf][r];
            }
        }
    }
#undef G1_STAGE
#undef G1_COMPUTE
}

// ---------------- softmax over T=800, one wave per row, in place; optionally emit bf16 W
__global__ __launch_bounds__(256) void softmax_kernel(float* __restrict__ S,
                                                      unsigned short* __restrict__ Wbf,
                                                      int writeWbf) {
    const int row = blockIdx.x * 4 + (threadIdx.x >> 6);   // 0..63999
    const int lane = threadIdx.x & 63;
    float* p = S + (size_t)row * NT;
    unsigned short* pw = Wbf + (size_t)row * NT;
    float v[13];
    float m = -INFINITY;
#pragma unroll
    for (int i = 0; i < 13; ++i) {
        int t = i * 64 + lane;
        v[i] = (t < NT) ? p[t] : -INFINITY;
        m = fmaxf(m, v[i]);
    }
#pragma unroll
    for (int off = 32; off; off >>= 1) m = fmaxf(m, __shfl_xor(m, off));
    float s = 0.f;
#pragma unroll
    for (int i = 0; i < 13; ++i) {
        int t = i * 64 + lane;
        float e = (t < NT) ? __expf(v[i] - m) : 0.f;
        v[i] = e;
        s += e;
    }
#pragma unroll
    for (int off = 32; off; off >>= 1) s += __shfl_xor(s, off);
    const float inv = 1.0f / s;
#pragma unroll
    for (int i = 0; i < 13; ++i) {
        int t = i * 64 + lane;
        if (t < NT) {
            float wv = v[i] * inv;
            p[t] = wv;
            if (writeWbf) pw[t] = f32_bf16(wv);
        }
    }
}

// ---------------- GEMM2 fast: ctx[b](1000x1024) = Wbf[b](1000x800) @ Cbf[b](1024x800)^T
// 256x256 tile, 8 waves (2Mx4N), BK=32, counted-vmcnt pipeline (4 loads/wave/stage).
__global__ __launch_bounds__(512) void gemm2_fast(const unsigned short* __restrict__ Wbf,
                                                  const unsigned short* __restrict__ Cbf,
                                                  float* __restrict__ O) {
    const int h = blockIdx.x;             // 1024 blocks
    const int L = (h & 7) * 128 + (h >> 3);
    const int b  = L >> 4;                // 0..63
    const int bm = (L >> 2) & 3;          // 0..3
    const int bn = L & 3;                 // 0..3
    const int tid = threadIdx.x;
    const int lane = tid & 63;
    const int w = tid >> 6;               // 0..7
    const int wr = w >> 2, wc = w & 3;

    // per buffer (ushort idx): As 0..8191 | Bs 8192..16383 (32KB); x2 = 64KB
    __shared__ unsigned short lds[2 * 16384];

    const int v0 = bm * 256, d0 = bn * 256;
    const unsigned short* Ag = Wbf + (size_t)b * NV * NT;
    const unsigned short* Bg = Cbf + ((size_t)b * ND + d0) * NT;

    f32x4 acc[8][4];
#pragma unroll
    for (int i = 0; i < 8; ++i)
#pragma unroll
        for (int j = 0; j < 4; ++j) acc[i][j] = (f32x4){0.f, 0.f, 0.f, 0.f};

    const int srow = lane >> 2;
    const int sslot = lane & 3;
    const int swz = (sslot ^ (srow & 3) ^ ((srow >> 2) & 3)) << 3;
    const int g = lane >> 4, rl = lane & 15;
    const int sx = (g ^ (rl & 3) ^ ((rl >> 2) & 3)) << 4;

#define G2_STAGE(K0, BUF)                                                     \
    {                                                                         \
        unsigned short* Lb = lds + (BUF) * 16384;                             \
        _Pragma("unroll")                                                     \
        for (int i = w; i < 16; i += 8) {                                     \
            int row = i * 16 + srow;                                          \
            int vrow = v0 + row; if (vrow > NV - 1) vrow = NV - 1;            \
            gload16(Ag + (size_t)vrow * NT + swz + (K0), Lb + i * 512);       \
            gload16(Bg + (size_t)row * NT + swz + (K0), Lb + 8192 + i * 512); \
        }                                                                     \
    }

#define G2_COMPUTE(BUF)                                                       \
    {                                                                         \
        const char* Lb = (const char*)(lds + (BUF) * 16384);                  \
        bf16x8 a[8], bq[4];                                                   \
        _Pragma("unroll")                                                     \
        for (int mf = 0; mf < 8; ++mf) {                                      \
            int off = (wr * 128 + mf * 16 + rl) * 64 + sx;                    \
            a[mf] = *(const bf16x8*)(Lb + off);                               \
        }                                                                     \
        _Pragma("unroll")                                                     \
        for (int nf = 0; nf < 4; ++nf) {                                      \
            int off = (wc * 64 + nf * 16 + rl) * 64 + sx;                     \
            bq[nf] = *(const bf16x8*)(Lb + 16384 + off);                      \
        }                                                                     \
        _Pragma("unroll")                                                     \
        for (int mf = 0; mf < 8; ++mf)                                        \
            _Pragma("unroll")                                                 \
            for (int nf = 0; nf < 4; ++nf)                                    \
                acc[mf][nf] = __builtin_amdgcn_mfma_f32_16x16x32_bf16(a[mf], bq[nf], acc[mf][nf], 0, 0, 0); \
    }

    G2_STAGE(0, 0);
    int cur = 0;
#pragma unroll 1
    for (int t = 0; t < 24; ++t) {
        G2_STAGE((t + 1) * 32, cur ^ 1);
        asm volatile("s_waitcnt vmcnt(4)\n\ts_barrier" ::: "memory");
        G2_COMPUTE(cur);
        asm volatile("s_waitcnt lgkmcnt(0)\n\ts_barrier" ::: "memory");
        cur ^= 1;
    }
    asm volatile("s_waitcnt vmcnt(0)\n\ts_barrier" ::: "memory");
    G2_COMPUTE(cur);

    float* Ob = O + (size_t)b * NV * ND;
#pragma unroll
    for (int mf = 0; mf < 8; ++mf) {
#pragma unroll
        for (int nf = 0; nf < 4; ++nf) {
#pragma unroll
            for (int r = 0; r < 4; ++r) {
                int v = v0 + wr * 128 + mf * 16 + g * 4 + r;
                int d = d0 + wc * 64 + nf * 16 + rl;
                if (v < NV) Ob[(size_t)v * ND + d] = acc[mf][nf][r];
            }
        }
    }
#undef G2_STAGE
#undef G2_COMPUTE
}

// ---------------- GEMM2 mid: A from Wbf (bf16, gload16), B converted inline from f32 C
__global__ __launch_bounds__(256) void gemm2_mid(const unsigned short* __restrict__ Wbf,
                                                 const float* __restrict__ C,
                                                 float* __restrict__ O) {
    const int h = blockIdx.x;
    const int L = (h & 7) * 512 + (h >> 3);
    const int bm = L & 7;
    const int bn = (L >> 3) & 7;
    const int b  = L >> 6;
    const int tid = threadIdx.x;
    const int lane = tid & 63;
    const int w = tid >> 6;
    const int wr = w >> 1, wc = w & 1;

    __shared__ unsigned short As[128 * 32];
    __shared__ unsigned short Bs[128][40];

    const int v0 = bm * 128, d0 = bn * 128;
    const unsigned short* Ag = Wbf + (size_t)b * NV * NT;
    const float* Cb = C + (size_t)b * ND * NT;

    f32x4 acc[4][4];
#pragma unroll
    for (int i = 0; i < 4; ++i)
#pragma unroll
        for (int j = 0; j < 4; ++j) acc[i][j] = (f32x4){0.f, 0.f, 0.f, 0.f};

    const int srow = lane >> 2;
    const int sslot = lane & 3;

    for (int k0 = 0; k0 < NT; k0 += 32) {
        for (int i = w; i < 8; i += 4) {
            int row = i * 16 + srow;
            int c = ((sslot ^ (row & 3)) << 3) + k0;
            int vrow = v0 + row; if (vrow > NV - 1) vrow = NV - 1;
            gload16(Ag + (size_t)vrow * NT + c, As + i * 512);
        }
#pragma unroll
        for (int r = 0; r < 4; ++r) {
            int idx = r * 256 + tid;
            int row = idx >> 3;
            int kq  = (idx & 7) << 2;
            const float4 f = *(const float4*)(Cb + (size_t)(d0 + row) * NT + k0 + kq);
            *(ushort4*)&Bs[row][kq] = make_ushort4(f32_bf16(f.x), f32_bf16(f.y), f32_bf16(f.z), f32_bf16(f.w));
        }
        __syncthreads();

        const int g = lane >> 4, rl = lane & 15;
        const int sx = (g ^ (rl & 3)) << 4;
        const int kk = g << 3;
        bf16x8 a[4], bfr[4];
#pragma unroll
        for (int mf = 0; mf < 4; ++mf) {
            int off = (wr * 64 + mf * 16 + rl) * 64 + sx;
            a[mf] = *(const bf16x8*)((const char*)As + off);
        }
#pragma unroll
        for (int nf = 0; nf < 4; ++nf) {
            int row = wc * 64 + nf * 16 + rl;
            bfr[nf] = *(const bf16x8*)&Bs[row][kk];
        }
#pragma unroll
        for (int mf = 0; mf < 4; ++mf)
#pragma unroll
            for (int nf = 0; nf < 4; ++nf)
                acc[mf][nf] = __builtin_amdgcn_mfma_f32_16x16x32_bf16(a[mf], bfr[nf], acc[mf][nf], 0, 0, 0);
        __syncthreads();
    }

    float* Ob = O + (size_t)b * NV * ND;
    const int g = lane >> 4, rl = lane & 15;
#pragma unroll
    for (int mf = 0; mf < 4; ++mf) {
#pragma unroll
        for (int nf = 0; nf < 4; ++nf) {
#pragma unroll
            for (int r = 0; r < 4; ++r) {
                int v = v0 + wr * 64 + mf * 16 + g * 4 + r;
                int d = d0 + wc * 64 + nf * 16 + rl;
                if (v < NV) Ob[(size_t)v * ND + d] = acc[mf][nf][r];
            }
        }
    }
}

// ---------------- GEMM2 slow (fallback): both operands converted inline from f32
__global__ __launch_bounds__(256) void gemm2_slow(const float* __restrict__ W,
                                                  const float* __restrict__ C,
                                                  float* __restrict__ O) {
    const int h = blockIdx.x;
    const int L = (h & 7) * 512 + (h >> 3);
    const int bm = L & 7;
    const int bn = (L >> 3) & 7;
    const int b  = L >> 6;
    const int tid = threadIdx.x;
    const int lane = tid & 63;
    const int wid = tid >> 6;
    const int wr = wid >> 1;
    const int wc = wid & 1;

    __shared__ unsigned short As[128][40];
    __shared__ unsigned short Bs[128][40];

    const float* Wb = W + (size_t)b * NV * NT;
    const float* Cb = C + (size_t)b * ND * NT;
    const int v0 = bm * 128;
    const int d0 = bn * 128;

    f32x4 acc[4][4];
#pragma unroll
    for (int i = 0; i < 4; ++i)
#pragma unroll
        for (int j = 0; j < 4; ++j) acc[i][j] = (f32x4){0.f, 0.f, 0.f, 0.f};

    for (int k0 = 0; k0 < NT; k0 += 32) {
#pragma unroll
        for (int r = 0; r < 4; ++r) {
            int idx = r * 256 + tid;
            int row = idx >> 3;
            int kq  = (idx & 7) << 2;
            int v = v0 + row; if (v > NV - 1) v = NV - 1;
            const float4 f = *(const float4*)(Wb + (size_t)v * NT + k0 + kq);
            *(ushort4*)&As[row][kq] = make_ushort4(f32_bf16(f.x), f32_bf16(f.y), f32_bf16(f.z), f32_bf16(f.w));
        }
#pragma unroll
        for (int r = 0; r < 4; ++r) {
            int idx = r * 256 + tid;
            int row = idx >> 3;
            int kq  = (idx & 7) << 2;
            const float4 f = *(const float4*)(Cb + (size_t)(d0 + row) * NT + k0 + kq);
            *(ushort4*)&Bs[row][kq] = make_ushort4(f32_bf16(f.x), f32_bf16(f.y), f32_bf16(f.z), f32_bf16(f.w));
        }
        __syncthreads();

        bf16x8 a[4], bfr[4];
        const int kk = (lane >> 4) << 3;
#pragma unroll
        for (int mf = 0; mf < 4; ++mf) {
            int row = wr * 64 + mf * 16 + (lane & 15);
            a[mf] = *(const bf16x8*)&As[row][kk];
        }
#pragma unroll
        for (int nf = 0; nf < 4; ++nf) {
            int row = wc * 64 + nf * 16 + (lane & 15);
            bfr[nf] = *(const bf16x8*)&Bs[row][kk];
        }
#pragma unroll
        for (int mf = 0; mf < 4; ++mf)
#pragma unroll
            for (int nf = 0; nf < 4; ++nf)
                acc[mf][nf] = __builtin_amdgcn_mfma_f32_16x16x32_bf16(a[mf], bfr[nf], acc[mf][nf], 0, 0, 0);
        __syncthreads();
    }

    float* Ob = O + (size_t)b * NV * ND;
#pragma unroll
    for (int mf = 0; mf < 4; ++mf) {
#pragma unroll
        for (int nf = 0; nf < 4; ++nf) {
#pragma unroll
            for (int r = 0; r < 4; ++r) {
                int v = v0 + wr * 64 + mf * 16 + (lane >> 4) * 4 + r;
                int d = d0 + wc * 64 + nf * 16 + (lane & 15);
                if (v < NV) Ob[(size_t)v * ND + d] = acc[mf][nf][r];
            }
        }
    }
}

extern "C" void kernel_launch(void* const* d_in, const int* in_sizes, int n_in,
                              void* d_out, int out_size, void* d_ws, size_t ws_size,
                              hipStream_t stream) {
    const float* Q = (const float*)d_in[0];          // (1000, 1024)
    const float* C = (const float*)d_in[1];          // (64, 1024, 800)
    float* ctx = (float*)d_out;                      // (64, 1000, 1024) = 262.1 MB
    float* wts = ctx + (size_t)NB * NV * ND;         // (64, 1000, 800)

    // gemm1 operands stashed in the (dead-until-gemm2) ctx region
    unsigned short* Cth = (unsigned short*)ctx;                    // [64][800][1024]
    unsigned short* Ctl = Cth + (size_t)NB * NT * ND;
    unsigned short* Qh  = Ctl + (size_t)NB * NT * ND;              // [1024][1024]
    unsigned short* Ql  = Qh + (size_t)1024 * ND;

    // gemm2 operands in workspace (sizes constant -> deterministic path choice)
    const size_t WbfBytes = (size_t)NB * NV * NT * 2;              // 102,400,000
    const size_t CbfBytes = (size_t)NB * ND * NT * 2;              // 104,857,600
    unsigned short* Wbf = (unsigned short*)d_ws;
    unsigned short* Cbf = (unsigned short*)((char*)d_ws + WbfBytes);
    const int wsFast = ws_size >= WbfBytes + CbfBytes;
    const int wsMid  = ws_size >= WbfBytes;

    prep_q<<<dim3(1024), 256, 0, stream>>>(Q, Qh, Ql);
    prep_c<<<dim3(16, 25, NB), 256, 0, stream>>>(C, Cth, Ctl, Cbf, wsFast);
    gemm1_kernel<<<dim3(2560), 256, 0, stream>>>(Qh, Ql, Cth, Ctl, wts);
    softmax_kernel<<<dim3(16000), 256, 0, stream>>>(wts, Wbf, wsMid);
    if (wsFast)      gemm2_fast<<<dim3(1024), 512, 0, stream>>>(Wbf, Cbf, ctx);
    else if (wsMid)  gemm2_mid<<<dim3(4096), 256, 0, stream>>>(Wbf, C, ctx);
    else             gemm2_slow<<<dim3(4096), 256, 0, stream>>>(wts, C, ctx);
}

// Round 7
// 658.132 us; speedup vs baseline: 1.2521x; 1.2521x over previous
//
#include <hip/hip_runtime.h>
#include <hip/hip_bf16.h>

typedef short bf16x8 __attribute__((ext_vector_type(8)));   // 8 bf16 in 4 VGPRs
typedef float f32x4 __attribute__((ext_vector_type(4)));

#define NV 1000
#define ND 1024
#define NT 800
#define NB 64

__device__ inline unsigned short f32_bf16(float f) {
    unsigned u = __builtin_bit_cast(unsigned, f);
    return (unsigned short)((u + 0x7FFFu + ((u >> 16) & 1u)) >> 16);
}
__device__ inline void split_bf16(float f, unsigned short& h, unsigned short& l) {
    unsigned u = __builtin_bit_cast(unsigned, f);
    unsigned hb = (u + 0x7FFFu + ((u >> 16) & 1u)) >> 16;
    h = (unsigned short)hb;
    float hf = __builtin_bit_cast(float, hb << 16);
    float lf = f - hf;
    unsigned ul = __builtin_bit_cast(unsigned, lf);
    l = (unsigned short)((ul + 0x7FFFu + ((ul >> 16) & 1u)) >> 16);
}

__device__ inline void gload16(const void* g, void* l) {
    __builtin_amdgcn_global_load_lds(
        (const __attribute__((address_space(1))) unsigned int*)g,
        (__attribute__((address_space(3))) unsigned int*)l, 16, 0, 0);
}

// ---------------- prep_q: pad Q (1000x1024) to 1024 rows, split into bf16 hi/lo
__global__ __launch_bounds__(256) void prep_q(const float* __restrict__ Q,
                                              unsigned short* __restrict__ Qh,
                                              unsigned short* __restrict__ Ql) {
    int idx = blockIdx.x * 256 + threadIdx.x;
    int row = idx >> 8;
    int c4 = (idx & 255) << 2;
    float4 f = make_float4(0.f, 0.f, 0.f, 0.f);
    if (row < NV) f = *(const float4*)(Q + (size_t)row * ND + c4);
    unsigned short h0,h1,h2,h3,l0,l1,l2,l3;
    split_bf16(f.x,h0,l0); split_bf16(f.y,h1,l1);
    split_bf16(f.z,h2,l2); split_bf16(f.w,h3,l3);
    *(ushort4*)(Qh + (size_t)row * ND + c4) = make_ushort4(h0,h1,h2,h3);
    *(ushort4*)(Ql + (size_t)row * ND + c4) = make_ushort4(l0,l1,l2,l3);
}

// ---------------- prep_c: transpose C[b] (1024,800) -> Ct[b] (800,1024) bf16 hi/lo
// Also (fast path) writes Cbf = bf16 copy of C in original [d][t] layout.
__global__ __launch_bounds__(256) void prep_c(const float* __restrict__ C,
                                              unsigned short* __restrict__ Cth,
                                              unsigned short* __restrict__ Ctl,
                                              unsigned short* __restrict__ Cbf,
                                              int writeCbf) {
    const int dt = blockIdx.x;   // 0..15
    const int tt = blockIdx.y;   // 0..24
    const int b  = blockIdx.z;
    const int tid = threadIdx.x;
    __shared__ float T[64][33];
    const float* Cb = C + (size_t)b * ND * NT;
    const int d0 = dt * 64, t0 = tt * 32;
#pragma unroll
    for (int r = 0; r < 2; ++r) {
        int idx = r * 256 + tid;
        int row = idx >> 3;               // d within tile, 0..63
        int c4 = (idx & 7) << 2;          // t within tile
        float4 f = *(const float4*)(Cb + (size_t)(d0 + row) * NT + t0 + c4);
        T[row][c4 + 0] = f.x; T[row][c4 + 1] = f.y;
        T[row][c4 + 2] = f.z; T[row][c4 + 3] = f.w;
        if (writeCbf) {
            *(ushort4*)(Cbf + ((size_t)b * ND + d0 + row) * NT + t0 + c4) =
                make_ushort4(f32_bf16(f.x), f32_bf16(f.y), f32_bf16(f.z), f32_bf16(f.w));
        }
    }
    __syncthreads();
#pragma unroll
    for (int r = 0; r < 2; ++r) {
        int idx = r * 256 + tid;
        int trow = idx >> 4;              // t within tile, 0..31
        int dc = (idx & 15) << 2;         // d within tile
        unsigned short h[4], l[4];
#pragma unroll
        for (int j = 0; j < 4; ++j) split_bf16(T[dc + j][trow], h[j], l[j]);
        size_t o = ((size_t)b * NT + t0 + trow) * ND + d0 + dc;
        *(ushort4*)(Cth + o) = make_ushort4(h[0],h[1],h[2],h[3]);
        *(ushort4*)(Ctl + o) = make_ushort4(l[0],l[1],l[2],l[3]);
    }
}

// ---------------- GEMM1: S[b](1000x800) = Q(1000x1024) @ C[b](1024x800)
// 3-term bf16 split. 8 waves (4Mx2N), tile 256x160, BK=32, 2 LDS buffers,
// counted-vmcnt pipeline (never vmcnt(0) in loop). 7 uniform gload16/wave/stage
// (52 runs + 4 benign duplicates); all (src,dst) precomputed in prologue.
// Buffer layout (bytes): Ah[0,16K) Al[16K,32K) Bh[32K,42K) Bl[42K,52K); 52KB x2.
__global__ __launch_bounds__(512) void gemm1_kernel(const unsigned short* __restrict__ Qh,
                                                    const unsigned short* __restrict__ Ql,
                                                    const unsigned short* __restrict__ Cth,
                                                    const unsigned short* __restrict__ Ctl,
                                                    float* __restrict__ S) {
    const int h = blockIdx.x;              // 1280 blocks = 8 XCDs x 160
    const int L = (h & 7) * 160 + (h >> 3);
    const int bm = L & 3;                  // 4 M-tiles (1024 padded rows)
    const int rest = L >> 2;
    const int bn = rest % 5;               // 5 T-tiles
    const int b  = rest / 5;               // 64 batches

    const int tid = threadIdx.x;
    const int lane = tid & 63;
    const int w = tid >> 6;                // 0..7
    const int wr = w >> 1, wc = w & 1;     // 4M x 2N

    __shared__ unsigned short lds[2 * 26624];   // 104 KB

    const int v0 = bm * 256, t0 = bn * 160;
    const unsigned short* Agh = Qh + (size_t)v0 * ND;
    const unsigned short* Agl = Ql + (size_t)v0 * ND;
    const unsigned short* Bgh = Cth + ((size_t)b * NT + t0) * ND;
    const unsigned short* Bgl = Ctl + ((size_t)b * NT + t0) * ND;

    f32x4 acc[4][5];
#pragma unroll
    for (int i = 0; i < 4; ++i)
#pragma unroll
        for (int j = 0; j < 5; ++j) acc[i][j] = (f32x4){0.f, 0.f, 0.f, 0.f};

    const int srow = lane >> 2;            // row within 16-row run
    const int sslot = lane & 3;            // physical 16B slot within 64B row
    const int swz = (sslot ^ (srow & 3) ^ ((srow >> 2) & 3)) << 3;  // source element off
    const int g = lane >> 4, rl = lane & 15;
    const int sx = (g ^ (rl & 3) ^ ((rl >> 2) & 3)) << 4;           // read byte slot

    // prologue: 7 (src,dst) pairs per wave, loop-invariant except k0
    const unsigned short* srcB[7];
    int dstU[7];
#pragma unroll
    for (int j = 0; j < 7; ++j) {
        int R = w * 7 + j; if (R >= 52) R -= 52;
        const unsigned short* sp; int du;
        if (R < 16)      { sp = Agh + (size_t)(R * 16 + srow) * ND;          du = R * 512; }
        else if (R < 32) { sp = Agl + (size_t)((R - 16) * 16 + srow) * ND;   du = 8192 + (R - 16) * 512; }
        else if (R < 42) { sp = Bgh + (size_t)((R - 32) * 16 + srow) * ND;   du = 16384 + (R - 32) * 512; }
        else             { sp = Bgl + (size_t)((R - 42) * 16 + srow) * ND;   du = 21504 + (R - 42) * 512; }
        srcB[j] = sp + swz;
        dstU[j] = du;
    }

#define G1_STAGE(K0, BUF)                                                     \
    {                                                                         \
        unsigned short* Lb = lds + (BUF) * 26624;                             \
        _Pragma("unroll")                                                     \
        for (int j = 0; j < 7; ++j) gload16(srcB[j] + (K0), Lb + dstU[j]);    \
    }

#define G1_COMPUTE(BUF)                                                       \
    {                                                                         \
        const char* Lb = (const char*)(lds + (BUF) * 26624);                  \
        bf16x8 ah[4], al[4], bh[5], bl[5];                                    \
        _Pragma("unroll")                                                     \
        for (int mf = 0; mf < 4; ++mf) {                                      \
            int off = (wr * 64 + mf * 16 + rl) * 64 + sx;                     \
            ah[mf] = *(const bf16x8*)(Lb + off);                              \
            al[mf] = *(const bf16x8*)(Lb + 16384 + off);                      \
        }                                                                     \
        _Pragma("unroll")                                                     \
        for (int nf = 0; nf < 5; ++nf) {                                      \
            int off = (wc * 80 + nf * 16 + rl) * 64 + sx;                     \
            bh[nf] = *(const bf16x8*)(Lb + 32768 + off);                      \
            bl[nf] = *(const bf16x8*)(Lb + 43008 + off);                      \
        }                                                                     \
        _Pragma("unroll")                                                     \
        for (int mf = 0; mf < 4; ++mf)                                        \
            _Pragma("unroll")                                                 \
            for (int nf = 0; nf < 5; ++nf) {                                  \
                acc[mf][nf] = __builtin_amdgcn_mfma_f32_16x16x32_bf16(ah[mf], bh[nf], acc[mf][nf], 0, 0, 0); \
                acc[mf][nf] = __builtin_amdgcn_mfma_f32_16x16x32_bf16(ah[mf], bl[nf], acc[mf][nf], 0, 0, 0); \
                acc[mf][nf] = __builtin_amdgcn_mfma_f32_16x16x32_bf16(al[mf], bh[nf], acc[mf][nf], 0, 0, 0); \
            }                                                                 \
    }

    G1_STAGE(0, 0);
    int cur = 0;
#pragma unroll 1
    for (int t = 0; t < 31; ++t) {
        G1_STAGE((t + 1) * 32, cur ^ 1);
        // tile t's 7 loads retired (<=7 outstanding = tile t+1's, still in flight)
        asm volatile("s_waitcnt vmcnt(7)\n\ts_barrier" ::: "memory");
        G1_COMPUTE(cur);
        // all ds_reads of buf cur retired before next iter overwrites it
        asm volatile("s_waitcnt lgkmcnt(0)\n\ts_barrier" ::: "memory");
        cur ^= 1;
    }
    asm volatile("s_waitcnt vmcnt(0)\n\ts_barrier" ::: "memory");
    G1_COMPUTE(cur);

    float* Sb = S + (size_t)b * NV * NT;
#pragma unroll
    for (int mf = 0; mf < 4; ++mf) {
#pragma unroll
        for (int nf = 0; nf < 5; ++nf) {
#pragma unroll
            for (int r = 0; r < 4; ++r) {
                int v = v0 + wr * 64 + mf * 16 + g * 4 + r;
                int t = t0 + wc * 80 + nf * 16 + rl;
                if (v < NV) Sb[(size_t)v * NT + t] = acc[mf][nf][r];
            }
        }
    }
#undef G1_STAGE
#undef G1_COMPUTE
}

// ---------------- softmax over T=800, one wave per row, in place; optionally emit bf16 W
__global__ __launch_bounds__(256) void softmax_kernel(float* __restrict__ S,
                                                      unsigned short* __restrict__ Wbf,
                                                      int writeWbf) {
    const int row = blockIdx.x * 4 + (threadIdx.x >> 6);   // 0..63999
    const int lane = threadIdx.x & 63;
    float* p = S + (size_t)row * NT;
    unsigned short* pw = Wbf + (size_t)row * NT;
    float v[13];
    float m = -INFINITY;
#pragma unroll
    for (int i = 0; i < 13; ++i) {
        int t = i * 64 + lane;
        v[i] = (t < NT) ? p[t] : -INFINITY;
        m = fmaxf(m, v[i]);
    }
#pragma unroll
    for (int off = 32; off; off >>= 1) m = fmaxf(m, __shfl_xor(m, off));
    float s = 0.f;
#pragma unroll
    for (int i = 0; i < 13; ++i) {
        int t = i * 64 + lane;
        float e = (t < NT) ? __expf(v[i] - m) : 0.f;
        v[i] = e;
        s += e;
    }
#pragma unroll
    for (int off = 32; off; off >>= 1) s += __shfl_xor(s, off);
    const float inv = 1.0f / s;
#pragma unroll
    for (int i = 0; i < 13; ++i) {
        int t = i * 64 + lane;
        if (t < NT) {
            float wv = v[i] * inv;
            p[t] = wv;
            if (writeWbf) pw[t] = f32_bf16(wv);
        }
    }
}

// ---------------- GEMM2 fast: ctx[b](1000x1024) = Wbf[b](1000x800) @ Cbf[b](1024x800)^T
// 256x256 tile, 8 waves (2Mx4N), BK=32, counted-vmcnt pipeline (4 loads/wave/stage).
__global__ __launch_bounds__(512) void gemm2_fast(const unsigned short* __restrict__ Wbf,
                                                  const unsigned short* __restrict__ Cbf,
                                                  float* __restrict__ O) {
    const int h = blockIdx.x;             // 1024 blocks
    const int L = (h & 7) * 128 + (h >> 3);
    const int b  = L >> 4;                // 0..63
    const int bm = (L >> 2) & 3;          // 0..3
    const int bn = L & 3;                 // 0..3
    const int tid = threadIdx.x;
    const int lane = tid & 63;
    const int w = tid >> 6;               // 0..7
    const int wr = w >> 2, wc = w & 3;

    // per buffer (ushort idx): As 0..8191 | Bs 8192..16383 (32KB); x2 = 64KB
    __shared__ unsigned short lds[2 * 16384];

    const int v0 = bm * 256, d0 = bn * 256;
    const unsigned short* Ag = Wbf + (size_t)b * NV * NT;
    const unsigned short* Bg = Cbf + ((size_t)b * ND + d0) * NT;

    f32x4 acc[8][4];
#pragma unroll
    for (int i = 0; i < 8; ++i)
#pragma unroll
        for (int j = 0; j < 4; ++j) acc[i][j] = (f32x4){0.f, 0.f, 0.f, 0.f};

    const int srow = lane >> 2;
    const int sslot = lane & 3;
    const int swz = (sslot ^ (srow & 3) ^ ((srow >> 2) & 3)) << 3;
    const int g = lane >> 4, rl = lane & 15;
    const int sx = (g ^ (rl & 3) ^ ((rl >> 2) & 3)) << 4;

#define G2_STAGE(K0, BUF)                                                     \
    {                                                                         \
        unsigned short* Lb = lds + (BUF) * 16384;                             \
        _Pragma("unroll")                                                     \
        for (int i = w; i < 16; i += 8) {                                     \
            int row = i * 16 + srow;                                          \
            int vrow = v0 + row; if (vrow > NV - 1) vrow = NV - 1;            \
            gload16(Ag + (size_t)vrow * NT + swz + (K0), Lb + i * 512);       \
            gload16(Bg + (size_t)row * NT + swz + (K0), Lb + 8192 + i * 512); \
        }                                                                     \
    }

#define G2_COMPUTE(BUF)                                                       \
    {                                                                         \
        const char* Lb = (const char*)(lds + (BUF) * 16384);                  \
        bf16x8 a[8], bq[4];                                                   \
        _Pragma("unroll")                                                     \
        for (int mf = 0; mf < 8; ++mf) {                                      \
            int off = (wr * 128 + mf * 16 + rl) * 64 + sx;                    \
            a[mf] = *(const bf16x8*)(Lb + off);                               \
        }                                                                     \
        _Pragma("unroll")                                                     \
        for (int nf = 0; nf < 4; ++nf) {                                      \
            int off = (wc * 64 + nf * 16 + rl) * 64 + sx;                     \
            bq[nf] = *(const bf16x8*)(Lb + 16384 + off);                      \
        }                                                                     \
        _Pragma("unroll")                                                     \
        for (int mf = 0; mf < 8; ++mf)                                        \
            _Pragma("unroll")                                                 \
            for (int nf = 0; nf < 4; ++nf)                                    \
                acc[mf][nf] = __builtin_amdgcn_mfma_f32_16x16x32_bf16(a[mf], bq[nf], acc[mf][nf], 0, 0, 0); \
    }

    G2_STAGE(0, 0);
    int cur = 0;
#pragma unroll 1
    for (int t = 0; t < 24; ++t) {
        G2_STAGE((t + 1) * 32, cur ^ 1);
        asm volatile("s_waitcnt vmcnt(4)\n\ts_barrier" ::: "memory");
        G2_COMPUTE(cur);
        asm volatile("s_waitcnt lgkmcnt(0)\n\ts_barrier" ::: "memory");
        cur ^= 1;
    }
    asm volatile("s_waitcnt vmcnt(0)\n\ts_barrier" ::: "memory");
    G2_COMPUTE(cur);

    float* Ob = O + (size_t)b * NV * ND;
#pragma unroll
    for (int mf = 0; mf < 8; ++mf) {
#pragma unroll
        for (int nf = 0; nf < 4; ++nf) {
#pragma unroll
            for (int r = 0; r < 4; ++r) {
                int v = v0 + wr * 128 + mf * 16 + g * 4 + r;
                int d = d0 + wc * 64 + nf * 16 + rl;
                if (v < NV) Ob[(size_t)v * ND + d] = acc[mf][nf][r];
            }
        }
    }
#undef G2_STAGE
#undef G2_COMPUTE
}

// ---------------- GEMM2 mid: A from Wbf (bf16, gload16), B converted inline from f32 C
__global__ __launch_bounds__(256) void gemm2_mid(const unsigned short* __restrict__ Wbf,
                                                 const float* __restrict__ C,
                                                 float* __restrict__ O) {
    const int h = blockIdx.x;
    const int L = (h & 7) * 512 + (h >> 3);
    const int bm = L & 7;
    const int bn = (L >> 3) & 7;
    const int b  = L >> 6;
    const int tid = threadIdx.x;
    const int lane = tid & 63;
    const int w = tid >> 6;
    const int wr = w >> 1, wc = w & 1;

    __shared__ unsigned short As[128 * 32];
    __shared__ unsigned short Bs[128][40];

    const int v0 = bm * 128, d0 = bn * 128;
    const unsigned short* Ag = Wbf + (size_t)b * NV * NT;
    const float* Cb = C + (size_t)b * ND * NT;

    f32x4 acc[4][4];
#pragma unroll
    for (int i = 0; i < 4; ++i)
#pragma unroll
        for (int j = 0; j < 4; ++j) acc[i][j] = (f32x4){0.f, 0.f, 0.f, 0.f};

    const int srow = lane >> 2;
    const int sslot = lane & 3;

    for (int k0 = 0; k0 < NT; k0 += 32) {
        for (int i = w; i < 8; i += 4) {
            int row = i * 16 + srow;
            int c = ((sslot ^ (row & 3)) << 3) + k0;
            int vrow = v0 + row; if (vrow > NV - 1) vrow = NV - 1;
            gload16(Ag + (size_t)vrow * NT + c, As + i * 512);
        }
#pragma unroll
        for (int r = 0; r < 4; ++r) {
            int idx = r * 256 + tid;
            int row = idx >> 3;
            int kq  = (idx & 7) << 2;
            const float4 f = *(const float4*)(Cb + (size_t)(d0 + row) * NT + k0 + kq);
            *(ushort4*)&Bs[row][kq] = make_ushort4(f32_bf16(f.x), f32_bf16(f.y), f32_bf16(f.z), f32_bf16(f.w));
        }
        __syncthreads();

        const int g = lane >> 4, rl = lane & 15;
        const int sx = (g ^ (rl & 3)) << 4;
        const int kk = g << 3;
        bf16x8 a[4], bfr[4];
#pragma unroll
        for (int mf = 0; mf < 4; ++mf) {
            int off = (wr * 64 + mf * 16 + rl) * 64 + sx;
            a[mf] = *(const bf16x8*)((const char*)As + off);
        }
#pragma unroll
        for (int nf = 0; nf < 4; ++nf) {
            int row = wc * 64 + nf * 16 + rl;
            bfr[nf] = *(const bf16x8*)&Bs[row][kk];
        }
#pragma unroll
        for (int mf = 0; mf < 4; ++mf)
#pragma unroll
            for (int nf = 0; nf < 4; ++nf)
                acc[mf][nf] = __builtin_amdgcn_mfma_f32_16x16x32_bf16(a[mf], bfr[nf], acc[mf][nf], 0, 0, 0);
        __syncthreads();
    }

    float* Ob = O + (size_t)b * NV * ND;
    const int g = lane >> 4, rl = lane & 15;
#pragma unroll
    for (int mf = 0; mf < 4; ++mf) {
#pragma unroll
        for (int nf = 0; nf < 4; ++nf) {
#pragma unroll
            for (int r = 0; r < 4; ++r) {
                int v = v0 + wr * 64 + mf * 16 + g * 4 + r;
                int d = d0 + wc * 64 + nf * 16 + rl;
                if (v < NV) Ob[(size_t)v * ND + d] = acc[mf][nf][r];
            }
        }
    }
}

// ---------------- GEMM2 slow (fallback): both operands converted inline from f32
__global__ __launch_bounds__(256) void gemm2_slow(const float* __restrict__ W,
                                                  const float* __restrict__ C,
                                                  float* __restrict__ O) {
    const int h = blockIdx.x;
    const int L = (h & 7) * 512 + (h >> 3);
    const int bm = L & 7;
    const int bn = (L >> 3) & 7;
    const int b  = L >> 6;
    const int tid = threadIdx.x;
    const int lane = tid & 63;
    const int wid = tid >> 6;
    const int wr = wid >> 1;
    const int wc = wid & 1;

    __shared__ unsigned short As[128][40];
    __shared__ unsigned short Bs[128][40];

    const float* Wb = W + (size_t)b * NV * NT;
    const float* Cb = C + (size_t)b * ND * NT;
    const int v0 = bm * 128;
    const int d0 = bn * 128;

    f32x4 acc[4][4];
#pragma unroll
    for (int i = 0; i < 4; ++i)
#pragma unroll
        for (int j = 0; j < 4; ++j) acc[i][j] = (f32x4){0.f, 0.f, 0.f, 0.f};

    for (int k0 = 0; k0 < NT; k0 += 32) {
#pragma unroll
        for (int r = 0; r < 4; ++r) {
            int idx = r * 256 + tid;
            int row = idx >> 3;
            int kq  = (idx & 7) << 2;
            int v = v0 + row; if (v > NV - 1) v = NV - 1;
            const float4 f = *(const float4*)(Wb + (size_t)v * NT + k0 + kq);
            *(ushort4*)&As[row][kq] = make_ushort4(f32_bf16(f.x), f32_bf16(f.y), f32_bf16(f.z), f32_bf16(f.w));
        }
#pragma unroll
        for (int r = 0; r < 4; ++r) {
            int idx = r * 256 + tid;
            int row = idx >> 3;
            int kq  = (idx & 7) << 2;
            const float4 f = *(const float4*)(Cb + (size_t)(d0 + row) * NT + k0 + kq);
            *(ushort4*)&Bs[row][kq] = make_ushort4(f32_bf16(f.x), f32_bf16(f.y), f32_bf16(f.z), f32_bf16(f.w));
        }
        __syncthreads();

        bf16x8 a[4], bfr[4];
        const int kk = (lane >> 4) << 3;
#pragma unroll
        for (int mf = 0; mf < 4; ++mf) {
            int row = wr * 64 + mf * 16 + (lane & 15);
            a[mf] = *(const bf16x8*)&As[row][kk];
        }
#pragma unroll
        for (int nf = 0; nf < 4; ++nf) {
            int row = wc * 64 + nf * 16 + (lane & 15);
            bfr[nf] = *(const bf16x8*)&Bs[row][kk];
        }
#pragma unroll
        for (int mf = 0; mf < 4; ++mf)
#pragma unroll
            for (int nf = 0; nf < 4; ++nf)
                acc[mf][nf] = __builtin_amdgcn_mfma_f32_16x16x32_bf16(a[mf], bfr[nf], acc[mf][nf], 0, 0, 0);
        __syncthreads();
    }

    float* Ob = O + (size_t)b * NV * ND;
#pragma unroll
    for (int mf = 0; mf < 4; ++mf) {
#pragma unroll
        for (int nf = 0; nf < 4; ++nf) {
#pragma unroll
            for (int r = 0; r < 4; ++r) {
                int v = v0 + wr * 64 + mf * 16 + (lane >> 4) * 4 + r;
                int d = d0 + wc * 64 + nf * 16 + (lane & 15);
                if (v < NV) Ob[(size_t)v * ND + d] = acc[mf][nf][r];
            }
        }
    }
}

extern "C" void kernel_launch(void* const* d_in, const int* in_sizes, int n_in,
                              void* d_out, int out_size, void* d_ws, size_t ws_size,
                              hipStream_t stream) {
    const float* Q = (const float*)d_in[0];          // (1000, 1024)
    const float* C = (const float*)d_in[1];          // (64, 1024, 800)
    float* ctx = (float*)d_out;                      // (64, 1000, 1024) = 262.1 MB
    float* wts = ctx + (size_t)NB * NV * ND;         // (64, 1000, 800)

    // gemm1 operands stashed in the (dead-until-gemm2) ctx region
    unsigned short* Cth = (unsigned short*)ctx;                    // [64][800][1024]
    unsigned short* Ctl = Cth + (size_t)NB * NT * ND;
    unsigned short* Qh  = Ctl + (size_t)NB * NT * ND;              // [1024][1024]
    unsigned short* Ql  = Qh + (size_t)1024 * ND;

    // gemm2 operands in workspace (sizes constant -> deterministic path choice)
    const size_t WbfBytes = (size_t)NB * NV * NT * 2;              // 102,400,000
    const size_t CbfBytes = (size_t)NB * ND * NT * 2;              // 104,857,600
    unsigned short* Wbf = (unsigned short*)d_ws;
    unsigned short* Cbf = (unsigned short*)((char*)d_ws + WbfBytes);
    const int wsFast = ws_size >= WbfBytes + CbfBytes;
    const int wsMid  = ws_size >= WbfBytes;

    prep_q<<<dim3(1024), 256, 0, stream>>>(Q, Qh, Ql);
    prep_c<<<dim3(16, 25, NB), 256, 0, stream>>>(C, Cth, Ctl, Cbf, wsFast);
    gemm1_kernel<<<dim3(1280), 512, 0, stream>>>(Qh, Ql, Cth, Ctl, wts);
    softmax_kernel<<<dim3(16000), 256, 0, stream>>>(wts, Wbf, wsMid);
    if (wsFast)      gemm2_fast<<<dim3(1024), 512, 0, stream>>>(Wbf, Cbf, ctx);
    else if (wsMid)  gemm2_mid<<<dim3(4096), 256, 0, stream>>>(Wbf, C, ctx);
    else             gemm2_slow<<<dim3(4096), 256, 0, stream>>>(wts, C, ctx);
}